// Round 1
// baseline (542.064 us; speedup 1.0000x reference)
//
#include <hip/hip_runtime.h>
#include <hip/hip_bf16.h>

// GCN 2-layer: h1 = relu(A_hat (x@W1) + b1); out = log_softmax(A_hat (h1@W2) + b2)
// A_hat = D^-1/2 (A + I) D^-1/2, deg = in-degree by dst (+ self loop).
// Strategy: build CSR (by dst) per launch, pull-based atomic-free aggregation.

#define F1 64
#define F2 16

// ---- degree histogram ----
__global__ void k_deg(const int* __restrict__ dst, int* __restrict__ deg, int E) {
  int e = blockIdx.x * blockDim.x + threadIdx.x;
  if (e < E) atomicAdd(&deg[dst[e]], 1);
}

// ---- per-chunk (1024 elems) sums for scan ----
__global__ void k_chunk_sum(const int* __restrict__ deg, int* __restrict__ csum, int N) {
  __shared__ int lds[256];
  int t = threadIdx.x;
  int base = blockIdx.x * 1024 + t * 4;
  int s = 0;
#pragma unroll
  for (int i = 0; i < 4; ++i) {
    int idx = base + i;
    if (idx < N) s += deg[idx];
  }
  lds[t] = s;
  __syncthreads();
  for (int off = 128; off > 0; off >>= 1) {
    if (t < off) lds[t] += lds[t + off];
    __syncthreads();
  }
  if (t == 0) csum[blockIdx.x] = lds[0];
}

// ---- exclusive scan of chunk sums (NB <= 128) ----
__global__ void k_scan_chunks(const int* __restrict__ csum, int* __restrict__ coff, int NB) {
  __shared__ int lds[128];
  int t = threadIdx.x;
  int v = (t < NB) ? csum[t] : 0;
  lds[t] = v;
  __syncthreads();
  for (int off = 1; off < 128; off <<= 1) {
    int add = (t >= off) ? lds[t - off] : 0;
    __syncthreads();
    lds[t] += add;
    __syncthreads();
  }
  if (t < NB) coff[t] = (t == 0) ? 0 : lds[t - 1];
}

// ---- final exclusive scan -> rowptr ----
__global__ void k_rowptr(const int* __restrict__ deg, const int* __restrict__ coff,
                         int* __restrict__ rowptr, int N, int E) {
  __shared__ int lds[256];
  int t = threadIdx.x;
  int base = blockIdx.x * 1024 + t * 4;
  int v[4];
  int s = 0;
#pragma unroll
  for (int i = 0; i < 4; ++i) {
    int idx = base + i;
    v[i] = (idx < N) ? deg[idx] : 0;
    s += v[i];
  }
  lds[t] = s;
  __syncthreads();
  for (int off = 1; off < 256; off <<= 1) {
    int add = (t >= off) ? lds[t - off] : 0;
    __syncthreads();
    lds[t] += add;
    __syncthreads();
  }
  int run = coff[blockIdx.x] + ((t == 0) ? 0 : lds[t - 1]);
#pragma unroll
  for (int i = 0; i < 4; ++i) {
    int idx = base + i;
    if (idx < N) rowptr[idx] = run;
    run += v[i];
  }
  if (blockIdx.x == 0 && t == 0) rowptr[N] = E;
}

// ---- dis = rsqrt(deg+1), in-place over the int deg buffer ----
__global__ void k_dis(int* __restrict__ degdis, int N) {
  int i = blockIdx.x * blockDim.x + threadIdx.x;
  if (i < N) {
    int d = degdis[i];
    ((float*)degdis)[i] = rsqrtf((float)(d + 1));
  }
}

// ---- CSR fill (counting sort by dst) ----
__global__ void k_fill(const int* __restrict__ src, const int* __restrict__ dst,
                       const int* __restrict__ rowptr, int* __restrict__ fill,
                       int* __restrict__ csr, int E) {
  int e = blockIdx.x * blockDim.x + threadIdx.x;
  if (e < E) {
    int d = dst[e];
    int pos = rowptr[d] + atomicAdd(&fill[d], 1);
    csr[pos] = src[e];
  }
}

// ---- GEMM1: out[N,64] = x[N,64] @ W[64,64] (no bias; bias after aggregation) ----
__global__ void k_gemm1(const float* __restrict__ x, const float* __restrict__ W,
                        float* __restrict__ out, int N) {
  __shared__ float w[64 * 64];
  for (int i = threadIdx.x; i < 64 * 64; i += 256) w[i] = W[i];
  __syncthreads();
  int lane = threadIdx.x & 63;
  int wv = threadIdx.x >> 6;  // wave in block (4 waves), 1 row per wave
  for (int n = blockIdx.x * 4 + wv; n < N; n += gridDim.x * 4) {
    const float4* xr = (const float4*)(x + (size_t)n * 64);
    float acc = 0.f;
#pragma unroll
    for (int k4 = 0; k4 < 16; ++k4) {
      float4 xv = xr[k4];  // wave-uniform broadcast
      acc = fmaf(xv.x, w[(k4 * 4 + 0) * 64 + lane], acc);
      acc = fmaf(xv.y, w[(k4 * 4 + 1) * 64 + lane], acc);
      acc = fmaf(xv.z, w[(k4 * 4 + 2) * 64 + lane], acc);
      acc = fmaf(xv.w, w[(k4 * 4 + 3) * 64 + lane], acc);
    }
    out[(size_t)n * 64 + lane] = acc;
  }
}

// ---- aggregation layer 1: wave per node, lane = feature; fused bias + relu ----
__global__ void k_agg1(const float* __restrict__ h, const float* __restrict__ dis,
                       const int* __restrict__ rowptr, const int* __restrict__ csr,
                       const float* __restrict__ b1, float* __restrict__ out, int N) {
  int gt = blockIdx.x * blockDim.x + threadIdx.x;
  int n = gt >> 6;
  int lane = gt & 63;
  if (n >= N) return;
  float dn = dis[n];
  float acc = dn * h[(size_t)n * 64 + lane];  // self loop (norm = dn*dn; outer dn applied below)
  int beg = rowptr[n], end = rowptr[n + 1];
  for (int e = beg; e < end; ++e) {
    int s = csr[e];
    acc = fmaf(dis[s], h[(size_t)s * 64 + lane], acc);
  }
  float v = fmaf(dn, acc, b1[lane]);
  out[(size_t)n * 64 + lane] = fmaxf(v, 0.f);
}

// ---- GEMM2: out[N,16] = h[N,64] @ W2[64,16] ----
__global__ void k_gemm2(const float* __restrict__ h, const float* __restrict__ W,
                        float* __restrict__ out, int N) {
  __shared__ float w[64 * 16];
  for (int i = threadIdx.x; i < 64 * 16; i += 256) w[i] = W[i];
  __syncthreads();
  int t = blockIdx.x * blockDim.x + threadIdx.x;
  int n = t >> 4;
  int j = t & 15;
  if (n >= N) return;
  const float4* hr = (const float4*)(h + (size_t)n * 64);
  float acc = 0.f;
#pragma unroll
  for (int k4 = 0; k4 < 16; ++k4) {
    float4 hv = hr[k4];  // quarter-wave-uniform
    acc = fmaf(hv.x, w[(k4 * 4 + 0) * 16 + j], acc);
    acc = fmaf(hv.y, w[(k4 * 4 + 1) * 16 + j], acc);
    acc = fmaf(hv.z, w[(k4 * 4 + 2) * 16 + j], acc);
    acc = fmaf(hv.w, w[(k4 * 4 + 3) * 16 + j], acc);
  }
  out[(size_t)n * 16 + j] = acc;
}

// ---- aggregation layer 2 + bias + log_softmax: quarter-wave (16 lanes) per node ----
__global__ void k_agg2(const float* __restrict__ h2, const float* __restrict__ dis,
                       const int* __restrict__ rowptr, const int* __restrict__ csr,
                       const float* __restrict__ b2, float* __restrict__ out, int N) {
  int t = blockIdx.x * blockDim.x + threadIdx.x;
  int n = t >> 4;
  int j = t & 15;
  if (n >= N) return;
  float dn = dis[n];
  float acc = dn * h2[(size_t)n * 16 + j];
  int beg = rowptr[n], end = rowptr[n + 1];
  for (int e = beg; e < end; ++e) {
    int s = csr[e];
    acc = fmaf(dis[s], h2[(size_t)s * 16 + j], acc);
  }
  float v = fmaf(dn, acc, b2[j]);
  // log_softmax over the 16 lanes of this node
  float m = v;
#pragma unroll
  for (int o = 1; o < 16; o <<= 1) m = fmaxf(m, __shfl_xor(m, o, 16));
  float ex = __expf(v - m);
  float sum = ex;
#pragma unroll
  for (int o = 1; o < 16; o <<= 1) sum += __shfl_xor(sum, o, 16);
  out[(size_t)n * 16 + j] = (v - m) - __logf(sum);
}

extern "C" void kernel_launch(void* const* d_in, const int* in_sizes, int n_in,
                              void* d_out, int out_size, void* d_ws, size_t ws_size,
                              hipStream_t stream) {
  const float* x = (const float*)d_in[0];
  const int* ei = (const int*)d_in[1];
  const float* W1 = (const float*)d_in[2];
  const float* b1 = (const float*)d_in[3];
  const float* W2 = (const float*)d_in[4];
  const float* b2 = (const float*)d_in[5];
  float* out = (float*)d_out;

  int N = in_sizes[0] / F1;   // 100000
  int E = in_sizes[1] / 2;    // 1600000
  const int* src = ei;
  const int* dst = ei + E;

  char* ws = (char*)d_ws;
  size_t o_deg    = 0;                                    // N int -> later reused as float dis
  size_t o_fill   = o_deg + (size_t)N * 4;                // N int
  size_t o_rowptr = o_fill + (size_t)N * 4;               // N+1 int
  size_t o_csum   = (o_rowptr + (size_t)(N + 1) * 4 + 255) & ~(size_t)255;
  size_t o_coff   = o_csum + 1024;
  size_t o_csr    = o_coff + 1024;                        // E int
  size_t o_h1     = (o_csr + (size_t)E * 4 + 255) & ~(size_t)255;  // N*64 f32
  size_t o_hr     = o_h1 + (size_t)N * 64 * 4;            // N*64 f32
  // h2 (N*16 f32) reuses o_h1 (h1 dead after agg1)

  int* deg      = (int*)(ws + o_deg);
  float* dis    = (float*)(ws + o_deg);
  int* fill     = (int*)(ws + o_fill);
  int* rowptr   = (int*)(ws + o_rowptr);
  int* csum     = (int*)(ws + o_csum);
  int* coff     = (int*)(ws + o_coff);
  int* csr      = (int*)(ws + o_csr);
  float* h1     = (float*)(ws + o_h1);
  float* hr     = (float*)(ws + o_hr);
  float* h2     = (float*)(ws + o_h1);

  int NB = (N + 1023) / 1024;  // 98 (must be <= 128 for k_scan_chunks)

  hipMemsetAsync(ws, 0, o_rowptr, stream);  // zero deg + fill

  k_deg<<<(E + 255) / 256, 256, 0, stream>>>(dst, deg, E);
  k_chunk_sum<<<NB, 256, 0, stream>>>(deg, csum, N);
  k_scan_chunks<<<1, 128, 0, stream>>>(csum, coff, NB);
  k_rowptr<<<NB, 256, 0, stream>>>(deg, coff, rowptr, N, E);
  k_dis<<<(N + 255) / 256, 256, 0, stream>>>(deg, N);
  k_fill<<<(E + 255) / 256, 256, 0, stream>>>(src, dst, rowptr, fill, csr, E);

  k_gemm1<<<2048, 256, 0, stream>>>(x, W1, h1, N);
  k_agg1<<<((size_t)N * 64 + 255) / 256, 256, 0, stream>>>(h1, dis, rowptr, csr, b1, hr, N);
  k_gemm2<<<((size_t)N * 16 + 255) / 256, 256, 0, stream>>>(hr, W2, h2, N);
  k_agg2<<<((size_t)N * 16 + 255) / 256, 256, 0, stream>>>(h2, dis, rowptr, csr, b2, out, N);
}

// Round 2
// 435.641 us; speedup vs baseline: 1.2443x; 1.2443x over previous
//
#include <hip/hip_runtime.h>
#include <hip/hip_bf16.h>
#include <hip/hip_fp16.h>

// GCN 2-layer: h1 = relu(A_hat (x@W1) + b1); out = log_softmax(A_hat (h1@W2) + b2)
// A_hat = D^-1/2 (A + I) D^-1/2. CSR built per launch; pull-based atomic-free agg.
// R2: latency-bound agg kernels -> 4-way MLP unroll + fp16 gather tables.

#define F1 64
#define F2 16

// ---- degree histogram ----
__global__ void k_deg(const int* __restrict__ dst, int* __restrict__ deg, int E) {
  int e = blockIdx.x * blockDim.x + threadIdx.x;
  if (e < E) atomicAdd(&deg[dst[e]], 1);
}

// ---- per-chunk (1024 elems) sums for scan ----
__global__ void k_chunk_sum(const int* __restrict__ deg, int* __restrict__ csum, int N) {
  __shared__ int lds[256];
  int t = threadIdx.x;
  int base = blockIdx.x * 1024 + t * 4;
  int s = 0;
#pragma unroll
  for (int i = 0; i < 4; ++i) {
    int idx = base + i;
    if (idx < N) s += deg[idx];
  }
  lds[t] = s;
  __syncthreads();
  for (int off = 128; off > 0; off >>= 1) {
    if (t < off) lds[t] += lds[t + off];
    __syncthreads();
  }
  if (t == 0) csum[blockIdx.x] = lds[0];
}

// ---- exclusive scan of chunk sums (NB <= 128) ----
__global__ void k_scan_chunks(const int* __restrict__ csum, int* __restrict__ coff, int NB) {
  __shared__ int lds[128];
  int t = threadIdx.x;
  int v = (t < NB) ? csum[t] : 0;
  lds[t] = v;
  __syncthreads();
  for (int off = 1; off < 128; off <<= 1) {
    int add = (t >= off) ? lds[t - off] : 0;
    __syncthreads();
    lds[t] += add;
    __syncthreads();
  }
  if (t < NB) coff[t] = (t == 0) ? 0 : lds[t - 1];
}

// ---- final exclusive scan -> rowptr ----
__global__ void k_rowptr(const int* __restrict__ deg, const int* __restrict__ coff,
                         int* __restrict__ rowptr, int N, int E) {
  __shared__ int lds[256];
  int t = threadIdx.x;
  int base = blockIdx.x * 1024 + t * 4;
  int v[4];
  int s = 0;
#pragma unroll
  for (int i = 0; i < 4; ++i) {
    int idx = base + i;
    v[i] = (idx < N) ? deg[idx] : 0;
    s += v[i];
  }
  lds[t] = s;
  __syncthreads();
  for (int off = 1; off < 256; off <<= 1) {
    int add = (t >= off) ? lds[t - off] : 0;
    __syncthreads();
    lds[t] += add;
    __syncthreads();
  }
  int run = coff[blockIdx.x] + ((t == 0) ? 0 : lds[t - 1]);
#pragma unroll
  for (int i = 0; i < 4; ++i) {
    int idx = base + i;
    if (idx < N) rowptr[idx] = run;
    run += v[i];
  }
  if (blockIdx.x == 0 && t == 0) rowptr[N] = E;
}

// ---- dis = rsqrt(deg+1), in-place over the int deg buffer ----
__global__ void k_dis(int* __restrict__ degdis, int N) {
  int i = blockIdx.x * blockDim.x + threadIdx.x;
  if (i < N) {
    int d = degdis[i];
    ((float*)degdis)[i] = rsqrtf((float)(d + 1));
  }
}

// ---- CSR fill (counting sort by dst) ----
__global__ void k_fill(const int* __restrict__ src, const int* __restrict__ dst,
                       const int* __restrict__ rowptr, int* __restrict__ fill,
                       int* __restrict__ csr, int E) {
  int e = blockIdx.x * blockDim.x + threadIdx.x;
  if (e < E) {
    int d = dst[e];
    int pos = rowptr[d] + atomicAdd(&fill[d], 1);
    csr[pos] = src[e];
  }
}

// ---- GEMM1: h1[N,64] = x[N,64] @ W1[64,64], stored fp16 (bias after agg) ----
__global__ void k_gemm1(const float* __restrict__ x, const float* __restrict__ W,
                        __half* __restrict__ out, int N) {
  __shared__ float w[64 * 64];
  for (int i = threadIdx.x; i < 64 * 64; i += 256) w[i] = W[i];
  __syncthreads();
  int lane = threadIdx.x & 63;
  int wv = threadIdx.x >> 6;  // 4 waves/block, 1 row per wave
  for (int n = blockIdx.x * 4 + wv; n < N; n += gridDim.x * 4) {
    const float4* xr = (const float4*)(x + (size_t)n * 64);
    float acc = 0.f;
#pragma unroll
    for (int k4 = 0; k4 < 16; ++k4) {
      float4 xv = xr[k4];  // wave-uniform broadcast
      acc = fmaf(xv.x, w[(k4 * 4 + 0) * 64 + lane], acc);
      acc = fmaf(xv.y, w[(k4 * 4 + 1) * 64 + lane], acc);
      acc = fmaf(xv.z, w[(k4 * 4 + 2) * 64 + lane], acc);
      acc = fmaf(xv.w, w[(k4 * 4 + 3) * 64 + lane], acc);
    }
    out[(size_t)n * 64 + lane] = __float2half(acc);
  }
}

// ---- agg layer 1: wave/node, lane=feature, edge loop unrolled x4 (MLP) ----
__global__ void k_agg1(const __half* __restrict__ h, const float* __restrict__ dis,
                       const int* __restrict__ rowptr, const int* __restrict__ csr,
                       const float* __restrict__ b1, float* __restrict__ out, int N) {
  int gt = blockIdx.x * blockDim.x + threadIdx.x;
  int n = gt >> 6;
  int lane = gt & 63;
  if (n >= N) return;
  float dn = dis[n];
  float acc = dn * __half2float(h[(size_t)n * 64 + lane]);  // self loop
  int beg = rowptr[n], end = rowptr[n + 1];
  int e = beg;
  for (; e + 4 <= end; e += 4) {
    int s0 = csr[e], s1 = csr[e + 1], s2 = csr[e + 2], s3 = csr[e + 3];
    float d0 = dis[s0], d1 = dis[s1], d2 = dis[s2], d3 = dis[s3];
    float v0 = __half2float(h[(size_t)s0 * 64 + lane]);
    float v1 = __half2float(h[(size_t)s1 * 64 + lane]);
    float v2 = __half2float(h[(size_t)s2 * 64 + lane]);
    float v3 = __half2float(h[(size_t)s3 * 64 + lane]);
    acc = fmaf(d0, v0, acc);
    acc = fmaf(d1, v1, acc);
    acc = fmaf(d2, v2, acc);
    acc = fmaf(d3, v3, acc);
  }
  for (; e < end; ++e) {
    int s = csr[e];
    acc = fmaf(dis[s], __half2float(h[(size_t)s * 64 + lane]), acc);
  }
  float v = fmaf(dn, acc, b1[lane]);
  out[(size_t)n * 64 + lane] = fmaxf(v, 0.f);
}

// ---- GEMM2: h2[N,16] = hr[N,64] @ W2[64,16], stored fp16 ----
__global__ void k_gemm2(const float* __restrict__ h, const float* __restrict__ W,
                        __half* __restrict__ out, int N) {
  __shared__ float w[64 * 16];
  for (int i = threadIdx.x; i < 64 * 16; i += 256) w[i] = W[i];
  __syncthreads();
  int t = blockIdx.x * blockDim.x + threadIdx.x;
  int n = t >> 4;
  int j = t & 15;
  if (n >= N) return;
  const float4* hr = (const float4*)(h + (size_t)n * 64);
  float acc = 0.f;
#pragma unroll
  for (int k4 = 0; k4 < 16; ++k4) {
    float4 hv = hr[k4];
    acc = fmaf(hv.x, w[(k4 * 4 + 0) * 16 + j], acc);
    acc = fmaf(hv.y, w[(k4 * 4 + 1) * 16 + j], acc);
    acc = fmaf(hv.z, w[(k4 * 4 + 2) * 16 + j], acc);
    acc = fmaf(hv.w, w[(k4 * 4 + 3) * 16 + j], acc);
  }
  out[(size_t)n * 16 + j] = __float2half(acc);
}

// ---- agg layer 2 + bias + log_softmax ----
// One wave per node: lane = j (feature 0..15) + 16*sub (edge substream 0..3).
// 4 independent gather chains per wave, zero divergence; shfl-reduce across subs.
__global__ void k_agg2(const __half* __restrict__ h2, const float* __restrict__ dis,
                       const int* __restrict__ rowptr, const int* __restrict__ csr,
                       const float* __restrict__ b2, float* __restrict__ out, int N) {
  int tid = threadIdx.x;
  int wv = tid >> 6;
  int lane = tid & 63;
  int j = lane & 15;
  int sub = lane >> 4;
  int n = blockIdx.x * 4 + wv;
  if (n >= N) return;
  float dn = dis[n];
  float acc = (sub == 0) ? dn * __half2float(h2[(size_t)n * 16 + j]) : 0.f;  // self loop
  int beg = rowptr[n], end = rowptr[n + 1];
  for (int e = beg + sub; e < end; e += 4) {
    int s = csr[e];
    acc = fmaf(dis[s], __half2float(h2[(size_t)s * 16 + j]), acc);
  }
  // reduce the 4 substreams (lanes j, j+16, j+32, j+48)
  acc += __shfl_xor(acc, 16);
  acc += __shfl_xor(acc, 32);
  float v = fmaf(dn, acc, b2[j]);
  // log_softmax over the 16 features (within each 16-lane group; all groups equal)
  float m = v;
#pragma unroll
  for (int o = 1; o < 16; o <<= 1) m = fmaxf(m, __shfl_xor(m, o, 16));
  float ex = __expf(v - m);
  float sum = ex;
#pragma unroll
  for (int o = 1; o < 16; o <<= 1) sum += __shfl_xor(sum, o, 16);
  if (sub == 0) out[(size_t)n * 16 + j] = (v - m) - __logf(sum);
}

extern "C" void kernel_launch(void* const* d_in, const int* in_sizes, int n_in,
                              void* d_out, int out_size, void* d_ws, size_t ws_size,
                              hipStream_t stream) {
  const float* x = (const float*)d_in[0];
  const int* ei = (const int*)d_in[1];
  const float* W1 = (const float*)d_in[2];
  const float* b1 = (const float*)d_in[3];
  const float* W2 = (const float*)d_in[4];
  const float* b2 = (const float*)d_in[5];
  float* out = (float*)d_out;

  int N = in_sizes[0] / F1;   // 100000
  int E = in_sizes[1] / 2;    // 1600000
  const int* src = ei;
  const int* dst = ei + E;

  char* ws = (char*)d_ws;
  size_t o_deg    = 0;                                    // N int -> later float dis
  size_t o_fill   = o_deg + (size_t)N * 4;                // N int
  size_t o_rowptr = o_fill + (size_t)N * 4;               // N+1 int
  size_t o_csum   = (o_rowptr + (size_t)(N + 1) * 4 + 255) & ~(size_t)255;
  size_t o_coff   = o_csum + 1024;
  size_t o_csr    = o_coff + 1024;                        // E int
  size_t o_h1     = (o_csr + (size_t)E * 4 + 255) & ~(size_t)255;  // N*64 fp16
  size_t o_hr     = (o_h1 + (size_t)N * 64 * 2 + 255) & ~(size_t)255;  // N*64 f32
  size_t o_h2     = (o_hr + (size_t)N * 64 * 4 + 255) & ~(size_t)255;  // N*16 fp16

  int* deg      = (int*)(ws + o_deg);
  float* dis    = (float*)(ws + o_deg);
  int* fill     = (int*)(ws + o_fill);
  int* rowptr   = (int*)(ws + o_rowptr);
  int* csum     = (int*)(ws + o_csum);
  int* coff     = (int*)(ws + o_coff);
  int* csr      = (int*)(ws + o_csr);
  __half* h1    = (__half*)(ws + o_h1);
  float* hr     = (float*)(ws + o_hr);
  __half* h2    = (__half*)(ws + o_h2);

  int NB = (N + 1023) / 1024;  // 98 (<=128 for k_scan_chunks)

  hipMemsetAsync(ws, 0, o_rowptr, stream);  // zero deg + fill

  k_deg<<<(E + 255) / 256, 256, 0, stream>>>(dst, deg, E);
  k_chunk_sum<<<NB, 256, 0, stream>>>(deg, csum, N);
  k_scan_chunks<<<1, 128, 0, stream>>>(csum, coff, NB);
  k_rowptr<<<NB, 256, 0, stream>>>(deg, coff, rowptr, N, E);
  k_dis<<<(N + 255) / 256, 256, 0, stream>>>(deg, N);
  k_fill<<<(E + 255) / 256, 256, 0, stream>>>(src, dst, rowptr, fill, csr, E);

  k_gemm1<<<2048, 256, 0, stream>>>(x, W1, h1, N);
  k_agg1<<<((size_t)N * 64 + 255) / 256, 256, 0, stream>>>(h1, dis, rowptr, csr, b1, hr, N);
  k_gemm2<<<((size_t)N * 16 + 255) / 256, 256, 0, stream>>>(hr, W2, h2, N);
  k_agg2<<<(N + 3) / 4, 256, 0, stream>>>(h2, dis, rowptr, csr, b2, out, N);
}